// Round 9
// baseline (614.555 us; speedup 1.0000x reference)
//
#include <hip/hip_runtime.h>

#define VOCAB   50000
#define LDIM    8921
#define DDIM    300
#define DPAD    320
#define KSZ     10
#define BATCH   8
#define TSEQ    2048
#define PADL    9
#define TPRIME  2057
#define TPADDED 2066
#define LPAD    8928

// ---- attn tiling
#define TSTG    32                 // t rows per tile
#define NTT     65                 // ceil(TPRIME/TSTG)
#define TALLOC  (NTT * TSTG)       // 2080 h rows per batch (tail rows zeroed by conv)
#define LBLK    70                 // ceil(LDIM/128) l-blocks

typedef short s8v __attribute__((ext_vector_type(8)));   // 8 x bf16 bits
typedef float f4v __attribute__((ext_vector_type(4)));

__device__ inline unsigned short f2bf(float f) {
  union { float f; unsigned u; } v; v.f = f;
  unsigned r = v.u + 0x7FFF + ((v.u >> 16) & 1);
  return (unsigned short)(r >> 16);
}

// ---- K1: embedding gather -> xp_bf16[b][tau][DPAD], zero-padded rows/cols
__global__ __launch_bounds__(256) void gather_kernel(
    const int* __restrict__ ids, const float* __restrict__ embed_w,
    unsigned short* __restrict__ xp) {
  int wid = blockIdx.x * 4 + (threadIdx.x >> 6);
  int lane = threadIdx.x & 63;
  int b = wid / TPADDED, tau = wid % TPADDED;
  bool inr = (tau >= PADL) && (tau < PADL + TSEQ);
  int row = inr ? ids[b * TSEQ + (tau - PADL)] : 0;
  const float* src = embed_w + (size_t)row * DDIM;
  unsigned short* dst = xp + ((size_t)b * TPADDED + tau) * DPAD;
#pragma unroll
  for (int j = 0; j < 3; ++j) {
    int c2 = (j * 64 + lane) * 2;
    if (c2 < DPAD) {
      float v0 = (inr && c2 < DDIM) ? src[c2] : 0.0f;
      float v1 = (inr && c2 + 1 < DDIM) ? src[c2 + 1] : 0.0f;
      unsigned pk = (unsigned)f2bf(v0) | ((unsigned)f2bf(v1) << 16);
      *(unsigned*)&dst[c2] = pk;
    }
  }
}

// ---- K2+K3 fused: conv weight transform + U transform
__global__ __launch_bounds__(256) void prep_kernel(
    const float* __restrict__ w, const float* __restrict__ U,
    unsigned short* __restrict__ wT, unsigned short* __restrict__ Ub) {
  int bid = blockIdx.x;
  if (bid < KSZ * DPAD) {
    int k = bid / DPAD, o = bid % DPAD;
    for (int i = threadIdx.x; i < DPAD; i += 256) {
      float v = (o < DDIM && i < DDIM) ? w[((size_t)o * DDIM + i) * KSZ + k] : 0.0f;
      wT[((size_t)k * DPAD + o) * DPAD + i] = f2bf(v);
    }
  } else {
    int l = bid - KSZ * DPAD;
    for (int d = threadIdx.x; d < DPAD; d += 256) {
      float v = (l < LDIM && d < DDIM) ? U[(size_t)l * DDIM + d] : 0.0f;
      Ub[(size_t)l * DPAD + d] = f2bf(v);
    }
  }
}

// ---- K4: conv via MFMA — balanced grid + distance-2 wT prefetch (r5 proven).
// Grid 208 = 8 x 26, <=1 block/CU, acc[5][5], manual Aping/Apong dist-2
// pipeline, NO tight launch_bounds (r3/r4 lesson: caps force scratch demotion).
#define CTN 80
#define CROWS 89          // CTN + KSZ - 1
#define CSTRIDE 328       // 656B/row -> benign 2-way conflicts
__global__ __launch_bounds__(256) void conv_mfma_kernel(
    const unsigned short* __restrict__ xp, const unsigned short* __restrict__ wT,
    const float* __restrict__ bias, unsigned short* __restrict__ h) {
  __shared__ unsigned short xls[CROWS * CSTRIDE];   // 58384 B
  int b = blockIdx.x & 7, tb = blockIdx.x >> 3;     // grid 208 = 8 x 26
  int t0 = tb * CTN;
  int tid = threadIdx.x;
  {
    const unsigned short* src = xp + (size_t)b * TPADDED * DPAD;
    for (int idx = tid; idx < CROWS * 40; idx += 256) {
      int rr = idx / 40, c8 = idx % 40;
      int tp = t0 + rr;
      int4 v = make_int4(0, 0, 0, 0);
      if (tp < TPADDED) v = *(const int4*)&src[(size_t)tp * DPAD + c8 * 8];
      *(int4*)&xls[rr * CSTRIDE + c8 * 8] = v;
    }
  }
  __syncthreads();
  int w = tid >> 6, lane = tid & 63;
  int l15 = lane & 15, quad = lane >> 4;
  int ob = w * 80;                                  // o-quadrant per wave
  f4v acc[5][5];
#pragma unroll
  for (int mf = 0; mf < 5; ++mf) {
    float bv[4];
#pragma unroll
    for (int rr = 0; rr < 4; ++rr) {
      int o = ob + mf * 16 + quad * 4 + rr;
      bv[rr] = (o < DDIM) ? bias[o] : 0.0f;
    }
#pragma unroll
    for (int nf = 0; nf < 5; ++nf) {
      acc[mf][nf][0] = bv[0]; acc[mf][nf][1] = bv[1];
      acc[mf][nf][2] = bv[2]; acc[mf][nf][3] = bv[3];
    }
  }
  // A-frag (kc,it,mf) at wl[kc*DPAD*DPAD + mf*16*DPAD + it*32]
  const unsigned short* wl = wT + (size_t)(ob + l15) * DPAD + quad * 8;
  s8v Aping[5], Apong[5];
#pragma unroll
  for (int mf = 0; mf < 5; ++mf) Aping[mf] = *(const s8v*)&wl[mf * 16 * DPAD];        // (0,0)
#pragma unroll
  for (int mf = 0; mf < 5; ++mf) Apong[mf] = *(const s8v*)&wl[mf * 16 * DPAD + 32];   // (0,1)
  for (int ii = 0; ii < 100; ii += 2) {
    // ---- even sub-iter: frags (ii) in Aping
    {
      int kc = ii / 10, it = ii % 10;
      s8v Bv[5];
#pragma unroll
      for (int nf = 0; nf < 5; ++nf)
        Bv[nf] = *(const s8v*)&xls[(nf * 16 + l15 + kc) * CSTRIDE + it * 32 + quad * 8];
#pragma unroll
      for (int mf = 0; mf < 5; ++mf)
#pragma unroll
        for (int nf = 0; nf < 5; ++nf)
          acc[mf][nf] = __builtin_amdgcn_mfma_f32_16x16x32_bf16(Aping[mf], Bv[nf], acc[mf][nf], 0, 0, 0);
      int p = ii + 2;
      if (p < 100) {
        int kp = p / 10, itp = p % 10;
        const unsigned short* wp = wl + (size_t)kp * (DPAD * DPAD) + itp * 32;
#pragma unroll
        for (int mf = 0; mf < 5; ++mf) Aping[mf] = *(const s8v*)&wp[mf * 16 * DPAD];
      }
    }
    // ---- odd sub-iter: frags (ii+1) in Apong
    {
      int kc = (ii + 1) / 10, it = (ii + 1) % 10;
      s8v Bv[5];
#pragma unroll
      for (int nf = 0; nf < 5; ++nf)
        Bv[nf] = *(const s8v*)&xls[(nf * 16 + l15 + kc) * CSTRIDE + it * 32 + quad * 8];
#pragma unroll
      for (int mf = 0; mf < 5; ++mf)
#pragma unroll
        for (int nf = 0; nf < 5; ++nf)
          acc[mf][nf] = __builtin_amdgcn_mfma_f32_16x16x32_bf16(Apong[mf], Bv[nf], acc[mf][nf], 0, 0, 0);
      int p = ii + 3;
      if (p < 100) {
        int kp = p / 10, itp = p % 10;
        const unsigned short* wp = wl + (size_t)kp * (DPAD * DPAD) + itp * 32;
#pragma unroll
        for (int mf = 0; mf < 5; ++mf) Apong[mf] = *(const s8v*)&wp[mf * 16 * DPAD];
      }
    }
  }
#pragma unroll
  for (int mf = 0; mf < 5; ++mf) {
    int obase = ob + mf * 16 + quad * 4;
#pragma unroll
    for (int nf = 0; nf < 5; ++nf) {
      int t = t0 + nf * 16 + l15;            // always < TALLOC (26x80 = 2080 exact)
      bool live = t < TPRIME;
      unsigned short pk[4];
#pragma unroll
      for (int rr = 0; rr < 4; ++rr)
        pk[rr] = live ? f2bf(fmaxf(acc[mf][nf][rr], 0.0f)) : (unsigned short)0;
      *(uint2*)&h[((size_t)b * TALLOC + t) * DPAD + obase] = *(uint2*)pk;
    }
  }
}

// ---- K5: scores (U . h) via MFMA + fused softmax-weighted mean.
// r9: NO-LDS restructure (common-mistake #7: h is L2-resident — 1.33MB/batch
// vs 4MB/XCD with the b=blockIdx&7 swizzle — so LDS staging + per-tile
// vmcnt(0)+barrier round-trip was the ~65x serializer; r8 falsified the
// occupancy theory: waves 2.2->4.4/SIMD moved nothing). B-fragments now load
// DIRECTLY from global: for fixed (kc,nf) the 64 lanes cover 16 rows x 64B
// = 16 fully-consumed cache lines; kc offsets (64B apart) fold into the
// offset: immediate. One RAW s_barrier per tile (no counter drain) keeps the
// 4 waves converged so the 20KB tile stays L1-shared. No DMA, no vmcnt,
// no swizzle. A[2][10] in AGPRs as before; unmasked softmax + (-23) corr.
__global__ __launch_bounds__(256, 3) void attn_mfma_kernel(
    const unsigned short* __restrict__ h, const unsigned short* __restrict__ Ub,
    const float* __restrict__ fcb, float* __restrict__ out) {
  int b = blockIdx.x & 7, lb = blockIdx.x >> 3;
  int tid = threadIdx.x;
  int w = tid >> 6, lane = tid & 63;
  int l15 = lane & 15, quad = lane >> 4;
  const unsigned short* hb = h + (size_t)b * TALLOC * DPAD;

  // A fragments (U) in registers/AGPRs: wave covers 32 l-rows
  s8v A[2][10];
  {
    int lr0 = lb * 128 + w * 32 + l15;
#pragma unroll
    for (int mf = 0; mf < 2; ++mf) {
      int lr = lr0 + mf * 16;
      if (lr >= LPAD) lr = LPAD - 1;          // clamped rows masked at store
      const unsigned short* up = Ub + (size_t)lr * DPAD + quad * 8;
#pragma unroll
      for (int kc = 0; kc < 10; ++kc)
        A[mf][kc] = *(const s8v*)&up[kc * 32];
    }
  }

  float se[2][4], sw[2][4];
#pragma unroll
  for (int mf = 0; mf < 2; ++mf)
#pragma unroll
    for (int r = 0; r < 4; ++r) { se[mf][r] = 0.0f; sw[mf][r] = 0.0f; }

  // B-fragment walking pointers: row (nf*16+l15), col chunk quad*8; kc*32
  // elems = kc*64 bytes folds into the load's offset immediate.
  const unsigned short* pb0 = hb + (size_t)l15 * DPAD + quad * 8;
  const unsigned short* pb1 = pb0 + 16 * DPAD;
  const f4v vzero = {0.0f, 0.0f, 0.0f, 0.0f};

  for (int t = 0; t < NTT; ++t) {
    f4v a00, a01, a10, a11;
    __builtin_amdgcn_s_setprio(1);
    {
      s8v Bv0 = *(const s8v*)&pb0[0];
      s8v Bv1 = *(const s8v*)&pb1[0];
      a00 = __builtin_amdgcn_mfma_f32_16x16x32_bf16(A[0][0], Bv0, vzero, 0, 0, 0);
      a01 = __builtin_amdgcn_mfma_f32_16x16x32_bf16(A[0][0], Bv1, vzero, 0, 0, 0);
      a10 = __builtin_amdgcn_mfma_f32_16x16x32_bf16(A[1][0], Bv0, vzero, 0, 0, 0);
      a11 = __builtin_amdgcn_mfma_f32_16x16x32_bf16(A[1][0], Bv1, vzero, 0, 0, 0);
    }
#pragma unroll
    for (int kc = 1; kc < 10; ++kc) {
      s8v Bv0 = *(const s8v*)&pb0[kc * 32];
      s8v Bv1 = *(const s8v*)&pb1[kc * 32];
      a00 = __builtin_amdgcn_mfma_f32_16x16x32_bf16(A[0][kc], Bv0, a00, 0, 0, 0);
      a01 = __builtin_amdgcn_mfma_f32_16x16x32_bf16(A[0][kc], Bv1, a01, 0, 0, 0);
      a10 = __builtin_amdgcn_mfma_f32_16x16x32_bf16(A[1][kc], Bv0, a10, 0, 0, 0);
      a11 = __builtin_amdgcn_mfma_f32_16x16x32_bf16(A[1][kc], Bv1, a11, 0, 0, 0);
    }
    __builtin_amdgcn_s_setprio(0);
    // unmasked fused softmax accumulation (tail h rows are exact zeros ->
    // s=0 -> e=1; corrected after the reduction)
#pragma unroll
    for (int r = 0; r < 4; ++r) {
      float s0 = a00[r], s1 = a01[r];
      float e0 = __expf(s0), e1 = __expf(s1);
      se[0][r] += e0 + e1;
      sw[0][r] = fmaf(e0, s0, sw[0][r]);
      sw[0][r] = fmaf(e1, s1, sw[0][r]);
      float s2 = a10[r], s3 = a11[r];
      float e2 = __expf(s2), e3 = __expf(s3);
      se[1][r] += e2 + e3;
      sw[1][r] = fmaf(e2, s2, sw[1][r]);
      sw[1][r] = fmaf(e3, s3, sw[1][r]);
    }
    pb0 += TSTG * DPAD;
    pb1 += TSTG * DPAD;
    // convergence barrier only (no memory drain): keeps the 4 waves on the
    // same tile so the 20KB tile is shared through L1.
    __builtin_amdgcn_s_barrier();
  }

  // reduce over the 16 t-columns (l15 lanes); subtract the 23 phantom columns
  // (TALLOC - TPRIME, each contributing exactly exp(0)=1) from the denominator.
#pragma unroll
  for (int mf = 0; mf < 2; ++mf)
#pragma unroll
    for (int r = 0; r < 4; ++r) {
      float a = se[mf][r], c = sw[mf][r];
#pragma unroll
      for (int off = 1; off < 16; off <<= 1) {
        a += __shfl_xor(a, off, 64);
        c += __shfl_xor(c, off, 64);
      }
      if (l15 == 0) {
        int l = lb * 128 + w * 32 + mf * 16 + quad * 4 + r;
        if (l < LDIM) out[(size_t)b * LDIM + l] = c / (a - 23.0f) + fcb[l];
      }
    }
}

extern "C" void kernel_launch(void* const* d_in, const int* in_sizes, int n_in,
                              void* d_out, int out_size, void* d_ws, size_t ws_size,
                              hipStream_t stream) {
  const int*   ids     = (const int*)d_in[0];
  const float* embed_w = (const float*)d_in[1];
  const float* conv_w  = (const float*)d_in[2];
  const float* conv_b  = (const float*)d_in[3];
  const float* U       = (const float*)d_in[4];
  const float* fc_bias = (const float*)d_in[5];
  float* out = (float*)d_out;

  unsigned char* p = (unsigned char*)d_ws;
  unsigned short* xp = (unsigned short*)p;                 p += (size_t)BATCH * TPADDED * DPAD * 2;
  unsigned short* hb = (unsigned short*)p;                 p += (size_t)BATCH * TALLOC * DPAD * 2;
  unsigned short* wT = (unsigned short*)p;                 p += (size_t)KSZ * DPAD * DPAD * 2;
  unsigned short* Ub = (unsigned short*)p;

  hipLaunchKernelGGL(gather_kernel, dim3(BATCH * TPADDED / 4), dim3(256), 0, stream,
                     ids, embed_w, xp);
  hipLaunchKernelGGL(prep_kernel, dim3(KSZ * DPAD + LPAD), dim3(256), 0, stream,
                     conv_w, U, wT, Ub);
  hipLaunchKernelGGL(conv_mfma_kernel, dim3(BATCH * 26), dim3(256), 0, stream,
                     xp, wT, conv_b, hb);
  hipLaunchKernelGGL(attn_mfma_kernel, dim3(BATCH * LBLK), dim3(256), 0, stream,
                     hb, Ub, fc_bias, out);
}

// Round 10
// 312.280 us; speedup vs baseline: 1.9680x; 1.9680x over previous
//
#include <hip/hip_runtime.h>

#define VOCAB   50000
#define LDIM    8921
#define DDIM    300
#define DPAD    320
#define KSZ     10
#define BATCH   8
#define TSEQ    2048
#define PADL    9
#define TPRIME  2057
#define TPADDED 2066
#define LPAD    8928

// ---- attn tiling
#define TSTG    32                 // t rows per LDS tile
#define NTT     65                 // ceil(TPRIME/TSTG)
#define TALLOC  (NTT * TSTG)       // 2080 h rows per batch (tail rows zeroed by conv)
#define LBLK    70                 // ceil(LDIM/128) l-blocks

typedef short s8v __attribute__((ext_vector_type(8)));   // 8 x bf16 bits
typedef float f4v __attribute__((ext_vector_type(4)));

typedef const __attribute__((address_space(1))) unsigned int* gas_ptr;
typedef __attribute__((address_space(3))) unsigned int* las_ptr;

__device__ inline unsigned short f2bf(float f) {
  union { float f; unsigned u; } v; v.f = f;
  unsigned r = v.u + 0x7FFF + ((v.u >> 16) & 1);
  return (unsigned short)(r >> 16);
}

// ---- K1: conv weight transform + U transform (fused prep)
__global__ __launch_bounds__(256) void prep_kernel(
    const float* __restrict__ w, const float* __restrict__ U,
    unsigned short* __restrict__ wT, unsigned short* __restrict__ Ub) {
  int bid = blockIdx.x;
  if (bid < KSZ * DPAD) {
    int k = bid / DPAD, o = bid % DPAD;
    for (int i = threadIdx.x; i < DPAD; i += 256) {
      float v = (o < DDIM && i < DDIM) ? w[((size_t)o * DDIM + i) * KSZ + k] : 0.0f;
      wT[((size_t)k * DPAD + o) * DPAD + i] = f2bf(v);
    }
  } else {
    int l = bid - KSZ * DPAD;
    for (int d = threadIdx.x; d < DPAD; d += 256) {
      float v = (l < LDIM && d < DDIM) ? U[(size_t)l * DDIM + d] : 0.0f;
      Ub[(size_t)l * DPAD + d] = f2bf(v);
    }
  }
}

// ---- K2: conv via MFMA with FUSED embedding gather (r10: xp round-trip and
// gather_kernel removed; staging reads embed_w[ids[.]] f32 directly, converts
// to bf16 in-register, ds_writes). Main loop unchanged from r5 (proven):
// grid 208 = 8 x 26, <=1 block/CU, acc[5][5], dist-2 Aping/Apong pipeline,
// NO tight launch_bounds (r3/r4: caps force scratch demotion).
#define CTN 80
#define CROWS 89          // CTN + KSZ - 1
#define CSTRIDE 328       // 656B/row -> benign 2-way conflicts
__global__ __launch_bounds__(256) void conv_mfma_kernel(
    const int* __restrict__ ids, const float* __restrict__ embed_w,
    const unsigned short* __restrict__ wT,
    const float* __restrict__ bias, unsigned short* __restrict__ h) {
  __shared__ unsigned short xls[CROWS * CSTRIDE];   // 58384 B
  int b = blockIdx.x & 7, tb = blockIdx.x >> 3;     // grid 208 = 8 x 26
  int t0 = tb * CTN;
  int tid = threadIdx.x;
  {
    const int* idsb = ids + b * TSEQ;
    for (int idx = tid; idx < CROWS * 40; idx += 256) {
      int rr = idx / 40, c8 = idx % 40;
      int tau = t0 + rr;
      bool inr = (tau >= PADL) && (tau < PADL + TSEQ);
      unsigned short pk[8];
      if (inr) {
        int row = idsb[tau - PADL];
        const float* src = embed_w + (size_t)row * DDIM + c8 * 8;
        // cols c8*8 .. c8*8+7; valid col < DDIM=300 (row stride 1200B is
        // 16B-aligned; float4 chunk at col 296 covers 296-299, still valid)
        float4 lo = (c8 * 8 + 3 < DDIM) ? *(const float4*)&src[0] : make_float4(0, 0, 0, 0);
        float4 hi = (c8 * 8 + 7 < DDIM) ? *(const float4*)&src[4] : make_float4(0, 0, 0, 0);
        pk[0] = f2bf(lo.x); pk[1] = f2bf(lo.y); pk[2] = f2bf(lo.z); pk[3] = f2bf(lo.w);
        pk[4] = f2bf(hi.x); pk[5] = f2bf(hi.y); pk[6] = f2bf(hi.z); pk[7] = f2bf(hi.w);
      } else {
#pragma unroll
        for (int e = 0; e < 8; ++e) pk[e] = 0;
      }
      *(int4*)&xls[rr * CSTRIDE + c8 * 8] = *(const int4*)pk;
    }
  }
  __syncthreads();
  int w = tid >> 6, lane = tid & 63;
  int l15 = lane & 15, quad = lane >> 4;
  int ob = w * 80;                                  // o-quadrant per wave
  f4v acc[5][5];
#pragma unroll
  for (int mf = 0; mf < 5; ++mf) {
    float bv[4];
#pragma unroll
    for (int rr = 0; rr < 4; ++rr) {
      int o = ob + mf * 16 + quad * 4 + rr;
      bv[rr] = (o < DDIM) ? bias[o] : 0.0f;
    }
#pragma unroll
    for (int nf = 0; nf < 5; ++nf) {
      acc[mf][nf][0] = bv[0]; acc[mf][nf][1] = bv[1];
      acc[mf][nf][2] = bv[2]; acc[mf][nf][3] = bv[3];
    }
  }
  // A-frag (kc,it,mf) at wl[kc*DPAD*DPAD + mf*16*DPAD + it*32]
  const unsigned short* wl = wT + (size_t)(ob + l15) * DPAD + quad * 8;
  s8v Aping[5], Apong[5];
#pragma unroll
  for (int mf = 0; mf < 5; ++mf) Aping[mf] = *(const s8v*)&wl[mf * 16 * DPAD];        // (0,0)
#pragma unroll
  for (int mf = 0; mf < 5; ++mf) Apong[mf] = *(const s8v*)&wl[mf * 16 * DPAD + 32];   // (0,1)
  for (int ii = 0; ii < 100; ii += 2) {
    // ---- even sub-iter: frags (ii) in Aping
    {
      int kc = ii / 10, it = ii % 10;
      s8v Bv[5];
#pragma unroll
      for (int nf = 0; nf < 5; ++nf)
        Bv[nf] = *(const s8v*)&xls[(nf * 16 + l15 + kc) * CSTRIDE + it * 32 + quad * 8];
#pragma unroll
      for (int mf = 0; mf < 5; ++mf)
#pragma unroll
        for (int nf = 0; nf < 5; ++nf)
          acc[mf][nf] = __builtin_amdgcn_mfma_f32_16x16x32_bf16(Aping[mf], Bv[nf], acc[mf][nf], 0, 0, 0);
      int p = ii + 2;
      if (p < 100) {
        int kp = p / 10, itp = p % 10;
        const unsigned short* wp = wl + (size_t)kp * (DPAD * DPAD) + itp * 32;
#pragma unroll
        for (int mf = 0; mf < 5; ++mf) Aping[mf] = *(const s8v*)&wp[mf * 16 * DPAD];
      }
    }
    // ---- odd sub-iter: frags (ii+1) in Apong
    {
      int kc = (ii + 1) / 10, it = (ii + 1) % 10;
      s8v Bv[5];
#pragma unroll
      for (int nf = 0; nf < 5; ++nf)
        Bv[nf] = *(const s8v*)&xls[(nf * 16 + l15 + kc) * CSTRIDE + it * 32 + quad * 8];
#pragma unroll
      for (int mf = 0; mf < 5; ++mf)
#pragma unroll
        for (int nf = 0; nf < 5; ++nf)
          acc[mf][nf] = __builtin_amdgcn_mfma_f32_16x16x32_bf16(Apong[mf], Bv[nf], acc[mf][nf], 0, 0, 0);
      int p = ii + 3;
      if (p < 100) {
        int kp = p / 10, itp = p % 10;
        const unsigned short* wp = wl + (size_t)kp * (DPAD * DPAD) + itp * 32;
#pragma unroll
        for (int mf = 0; mf < 5; ++mf) Apong[mf] = *(const s8v*)&wp[mf * 16 * DPAD];
      }
    }
  }
#pragma unroll
  for (int mf = 0; mf < 5; ++mf) {
    int obase = ob + mf * 16 + quad * 4;
#pragma unroll
    for (int nf = 0; nf < 5; ++nf) {
      int t = t0 + nf * 16 + l15;            // always < TALLOC (26x80 = 2080 exact)
      bool live = t < TPRIME;
      unsigned short pk[4];
#pragma unroll
      for (int rr = 0; rr < 4; ++rr)
        pk[rr] = live ? f2bf(fmaxf(acc[mf][nf][rr], 0.0f)) : (unsigned short)0;
      *(uint2*)&h[((size_t)b * TALLOC + t) * DPAD + obase] = *(uint2*)pk;
    }
  }
}

// ---- K3: scores (U . h) via MFMA + fused softmax-weighted mean.
// r10: DIST-2 COUNTED-VMCNT pipeline (T3/T4). r9 proved LDS staging is
// necessary (direct-global = 449us); r5-r8 proved the structure's residual
// stall is the per-tile vmcnt(0) drain: DMA(t+1) issued at tile t start and
// drained same-tile has only ~1000cyc cover, and barrier-locked blocks take
// the latency tail simultaneously. Now: 3 buffers, issue DMA(t+2) at tile t,
// drain with vmcnt(5) (waits only for DMA(t+1), issued a FULL tile earlier).
// Per-block tile-phase stagger (tiles are order-independent sums) decorrelates
// L2 access across blocks. LDS 61440B -> 2 blocks/CU (r8: occupancy not the
// lever). A[2][10] in AGPRs; unmasked softmax + (-23) phantom correction.
__global__ __launch_bounds__(256) void attn_mfma_kernel(
    const unsigned short* __restrict__ h, const unsigned short* __restrict__ Ub,
    const float* __restrict__ fcb, float* __restrict__ out) {
  __shared__ unsigned short hls[3 * TSTG * DPAD];   // 3 x 10240 elems = 61440B
  int b = blockIdx.x & 7, lb = blockIdx.x >> 3;
  int tid = threadIdx.x;
  int w = tid >> 6, lane = tid & 63;
  int l15 = lane & 15, quad = lane >> 4;
  const unsigned short* hb = h + (size_t)b * TALLOC * DPAD;

  // A fragments (U): wave covers 32 l-rows (lives in AGPRs, r6 finding)
  s8v A[2][10];
  {
    int lr0 = lb * 128 + w * 32 + l15;
#pragma unroll
    for (int mf = 0; mf < 2; ++mf) {
      int lr = lr0 + mf * 16;
      if (lr >= LPAD) lr = LPAD - 1;          // clamped rows masked at store
      const unsigned short* up = Ub + (size_t)lr * DPAD + quad * 8;
#pragma unroll
      for (int kc = 0; kc < 10; ++kc)
        A[mf][kc] = *(const s8v*)&up[kc * 32];
    }
  }
  // make the outstanding-vmem count deterministic before DMA issues
  asm volatile("s_waitcnt vmcnt(0)" ::: "memory");

  // DMA staging map: wave w fills LDS elems [w*2560, w*2560+2560) in 5 x 1KB.
  // lane's LDS chunk g = w*320 + j*64 + lane -> row r = g/40, chunk c = g%40;
  // global source chunk = c ^ (r&7)  (involution, same XOR on read side)
  int srcoff[5];
#pragma unroll
  for (int j = 0; j < 5; ++j) {
    int g = w * 320 + j * 64 + lane;
    int r = g / 40, c = g % 40;
    srcoff[j] = r * DPAD + ((c ^ (r & 7)) * 8);
  }

  // tile-phase stagger: block processes tiles phase, phase+1, ... (mod NTT)
  int phase = lb % NTT;
  int tp0 = phase;                          // phys tile for logical 0
  int tp1 = (phase + 1 < NTT) ? phase + 1 : phase + 1 - NTT;

  // prologue: DMA phys(0) -> buf0, phys(1) -> buf1; wait for buf0 only
#pragma unroll
  for (int j = 0; j < 5; ++j)
    __builtin_amdgcn_global_load_lds(
        (gas_ptr)(const void*)(hb + (size_t)tp0 * (TSTG * DPAD) + srcoff[j]),
        (las_ptr)(void*)&hls[w * 2560 + j * 512], 16, 0, 0);
#pragma unroll
  for (int j = 0; j < 5; ++j)
    __builtin_amdgcn_global_load_lds(
        (gas_ptr)(const void*)(hb + (size_t)tp1 * (TSTG * DPAD) + srcoff[j]),
        (las_ptr)(void*)&hls[10240 + w * 2560 + j * 512], 16, 0, 0);
  asm volatile("s_waitcnt vmcnt(5)" ::: "memory");
  __builtin_amdgcn_s_barrier();

  float se[2][4], sw[2][4];
#pragma unroll
  for (int mf = 0; mf < 2; ++mf)
#pragma unroll
    for (int r = 0; r < 4; ++r) { se[mf][r] = 0.0f; sw[mf][r] = 0.0f; }

  int xr8 = (l15 & 7) * 8;            // read-side XOR (elem units)
  int rowb0 = l15 * DPAD;             // nf=0 row base
  int rowb1 = (16 + l15) * DPAD;      // nf=1 row base
  int cur = 0, d2 = 2;                // buf indices: current, and t+2 target
  int tp2 = (phase + 2 < NTT) ? phase + 2 : phase + 2 - NTT;  // phys tile t+2
  const f4v vzero = {0.0f, 0.0f, 0.0f, 0.0f};

  for (int t = 0; t < NTT; ++t) {
    // issue DMA for phys(t+2) into buf d2 (two full tiles of flight time)
    if (t + 2 < NTT) {
      const unsigned short* src = hb + (size_t)tp2 * (TSTG * DPAD);
      int dstb = d2 * 10240 + w * 2560;
#pragma unroll
      for (int j = 0; j < 5; ++j)
        __builtin_amdgcn_global_load_lds((gas_ptr)(const void*)(src + srcoff[j]),
                                         (las_ptr)(void*)&hls[dstb + j * 512],
                                         16, 0, 0);
      tp2 = (tp2 + 1 < NTT) ? tp2 + 1 : 0;
    }
    const unsigned short* bufc = &hls[cur * 10240];
    f4v a00, a01, a10, a11;
    __builtin_amdgcn_s_setprio(1);
    {
      int ko = (quad * 8) ^ xr8;
      s8v Bv0 = *(const s8v*)&bufc[rowb0 + ko];
      s8v Bv1 = *(const s8v*)&bufc[rowb1 + ko];
      a00 = __builtin_amdgcn_mfma_f32_16x16x32_bf16(A[0][0], Bv0, vzero, 0, 0, 0);
      a01 = __builtin_amdgcn_mfma_f32_16x16x32_bf16(A[0][0], Bv1, vzero, 0, 0, 0);
      a10 = __builtin_amdgcn_mfma_f32_16x16x32_bf16(A[1][0], Bv0, vzero, 0, 0, 0);
      a11 = __builtin_amdgcn_mfma_f32_16x16x32_bf16(A[1][0], Bv1, vzero, 0, 0, 0);
    }
#pragma unroll
    for (int kc = 1; kc < 10; ++kc) {
      int ko = (kc * 32 + quad * 8) ^ xr8;
      s8v Bv0 = *(const s8v*)&bufc[rowb0 + ko];
      s8v Bv1 = *(const s8v*)&bufc[rowb1 + ko];
      a00 = __builtin_amdgcn_mfma_f32_16x16x32_bf16(A[0][kc], Bv0, a00, 0, 0, 0);
      a01 = __builtin_amdgcn_mfma_f32_16x16x32_bf16(A[0][kc], Bv1, a01, 0, 0, 0);
      a10 = __builtin_amdgcn_mfma_f32_16x16x32_bf16(A[1][kc], Bv0, a10, 0, 0, 0);
      a11 = __builtin_amdgcn_mfma_f32_16x16x32_bf16(A[1][kc], Bv1, a11, 0, 0, 0);
    }
    __builtin_amdgcn_s_setprio(0);
    // unmasked fused softmax accumulation (tail h rows are exact zeros ->
    // s=0 -> e=1; corrected after the reduction)
#pragma unroll
    for (int r = 0; r < 4; ++r) {
      float s0 = a00[r], s1 = a01[r];
      float e0 = __expf(s0), e1 = __expf(s1);
      se[0][r] += e0 + e1;
      sw[0][r] = fmaf(e0, s0, sw[0][r]);
      sw[0][r] = fmaf(e1, s1, sw[0][r]);
      float s2 = a10[r], s3 = a11[r];
      float e2 = __expf(s2), e3 = __expf(s3);
      se[1][r] += e2 + e3;
      sw[1][r] = fmaf(e2, s2, sw[1][r]);
      sw[1][r] = fmaf(e3, s3, sw[1][r]);
    }
    // counted drain: wait only for DMA(t+1) (issued one full tile ago);
    // the 5 loads for t+2 stay in flight across the barrier (T4).
    if (t + 2 < NTT) {
      asm volatile("s_waitcnt vmcnt(5)" ::: "memory");
    } else {
      asm volatile("s_waitcnt vmcnt(0)" ::: "memory");
    }
    __builtin_amdgcn_s_barrier();
    cur = (cur + 1 < 3) ? cur + 1 : 0;
    d2 = (d2 + 1 < 3) ? d2 + 1 : 0;
  }

  // reduce over the 16 t-columns (l15 lanes); subtract the 23 phantom columns
  // (TALLOC - TPRIME, each contributing exactly exp(0)=1) from the denominator.
#pragma unroll
  for (int mf = 0; mf < 2; ++mf)
#pragma unroll
    for (int r = 0; r < 4; ++r) {
      float a = se[mf][r], c = sw[mf][r];
#pragma unroll
      for (int off = 1; off < 16; off <<= 1) {
        a += __shfl_xor(a, off, 64);
        c += __shfl_xor(c, off, 64);
      }
      if (l15 == 0) {
        int l = lb * 128 + w * 32 + mf * 16 + quad * 4 + r;
        if (l < LDIM) out[(size_t)b * LDIM + l] = c / (a - 23.0f) + fcb[l];
      }
    }
}

extern "C" void kernel_launch(void* const* d_in, const int* in_sizes, int n_in,
                              void* d_out, int out_size, void* d_ws, size_t ws_size,
                              hipStream_t stream) {
  const int*   ids     = (const int*)d_in[0];
  const float* embed_w = (const float*)d_in[1];
  const float* conv_w  = (const float*)d_in[2];
  const float* conv_b  = (const float*)d_in[3];
  const float* U       = (const float*)d_in[4];
  const float* fc_bias = (const float*)d_in[5];
  float* out = (float*)d_out;

  unsigned char* p = (unsigned char*)d_ws;
  unsigned short* hb = (unsigned short*)p;                 p += (size_t)BATCH * TALLOC * DPAD * 2;
  unsigned short* wT = (unsigned short*)p;                 p += (size_t)KSZ * DPAD * DPAD * 2;
  unsigned short* Ub = (unsigned short*)p;

  hipLaunchKernelGGL(prep_kernel, dim3(KSZ * DPAD + LPAD), dim3(256), 0, stream,
                     conv_w, U, wT, Ub);
  hipLaunchKernelGGL(conv_mfma_kernel, dim3(BATCH * 26), dim3(256), 0, stream,
                     ids, embed_w, wT, conv_b, hb);
  hipLaunchKernelGGL(attn_mfma_kernel, dim3(BATCH * LBLK), dim3(256), 0, stream,
                     hb, Ub, fc_bias, out);
}

// Round 11
// 283.600 us; speedup vs baseline: 2.1670x; 1.1011x over previous
//
#include <hip/hip_runtime.h>

#define VOCAB   50000
#define LDIM    8921
#define DDIM    300
#define DPAD    320
#define KSZ     10
#define BATCH   8
#define TSEQ    2048
#define PADL    9
#define TPRIME  2057
#define TPADDED 2066
#define LPAD    8928

// ---- attn tiling
#define TSTG    32                 // t rows per LDS tile
#define NTT     65                 // ceil(TPRIME/TSTG)
#define TALLOC  (NTT * TSTG)       // 2080 h rows per batch (tail rows zeroed by conv)
#define LBLK    70                 // ceil(LDIM/128) l-blocks

typedef short s8v __attribute__((ext_vector_type(8)));   // 8 x bf16 bits
typedef float f4v __attribute__((ext_vector_type(4)));

typedef const __attribute__((address_space(1))) unsigned int* gas_ptr;
typedef __attribute__((address_space(3))) unsigned int* las_ptr;

__device__ inline unsigned short f2bf(float f) {
  union { float f; unsigned u; } v; v.f = f;
  unsigned r = v.u + 0x7FFF + ((v.u >> 16) & 1);
  return (unsigned short)(r >> 16);
}

// ---- K1: conv weight transform + U transform (fused prep)
__global__ __launch_bounds__(256) void prep_kernel(
    const float* __restrict__ w, const float* __restrict__ U,
    unsigned short* __restrict__ wT, unsigned short* __restrict__ Ub) {
  int bid = blockIdx.x;
  if (bid < KSZ * DPAD) {
    int k = bid / DPAD, o = bid % DPAD;
    for (int i = threadIdx.x; i < DPAD; i += 256) {
      float v = (o < DDIM && i < DDIM) ? w[((size_t)o * DDIM + i) * KSZ + k] : 0.0f;
      wT[((size_t)k * DPAD + o) * DPAD + i] = f2bf(v);
    }
  } else {
    int l = bid - KSZ * DPAD;
    for (int d = threadIdx.x; d < DPAD; d += 256) {
      float v = (l < LDIM && d < DDIM) ? U[(size_t)l * DDIM + d] : 0.0f;
      Ub[(size_t)l * DPAD + d] = f2bf(v);
    }
  }
}

// ---- K2: conv via MFMA with fused embedding gather (r10: proven, rest
// 167->161us). Staging reads embed_w[ids[.]] f32 directly, converts to bf16
// in-register, ds_writes. Main loop = r5 proven structure: grid 208 = 8 x 26,
// <=1 block/CU balanced, acc[5][5], dist-2 Aping/Apong wT pipeline, NO tight
// launch_bounds (r3/r4: caps force scratch demotion).
#define CTN 80
#define CROWS 89          // CTN + KSZ - 1
#define CSTRIDE 328       // 656B/row -> benign 2-way conflicts
__global__ __launch_bounds__(256) void conv_mfma_kernel(
    const int* __restrict__ ids, const float* __restrict__ embed_w,
    const unsigned short* __restrict__ wT,
    const float* __restrict__ bias, unsigned short* __restrict__ h) {
  __shared__ unsigned short xls[CROWS * CSTRIDE];   // 58384 B
  int b = blockIdx.x & 7, tb = blockIdx.x >> 3;     // grid 208 = 8 x 26
  int t0 = tb * CTN;
  int tid = threadIdx.x;
  {
    const int* idsb = ids + b * TSEQ;
    for (int idx = tid; idx < CROWS * 40; idx += 256) {
      int rr = idx / 40, c8 = idx % 40;
      int tau = t0 + rr;
      bool inr = (tau >= PADL) && (tau < PADL + TSEQ);
      unsigned short pk[8];
      if (inr) {
        int row = idsb[tau - PADL];
        const float* src = embed_w + (size_t)row * DDIM + c8 * 8;
        float4 lo = (c8 * 8 + 3 < DDIM) ? *(const float4*)&src[0] : make_float4(0, 0, 0, 0);
        float4 hi = (c8 * 8 + 7 < DDIM) ? *(const float4*)&src[4] : make_float4(0, 0, 0, 0);
        pk[0] = f2bf(lo.x); pk[1] = f2bf(lo.y); pk[2] = f2bf(lo.z); pk[3] = f2bf(lo.w);
        pk[4] = f2bf(hi.x); pk[5] = f2bf(hi.y); pk[6] = f2bf(hi.z); pk[7] = f2bf(hi.w);
      } else {
#pragma unroll
        for (int e = 0; e < 8; ++e) pk[e] = 0;
      }
      *(int4*)&xls[rr * CSTRIDE + c8 * 8] = *(const int4*)pk;
    }
  }
  __syncthreads();
  int w = tid >> 6, lane = tid & 63;
  int l15 = lane & 15, quad = lane >> 4;
  int ob = w * 80;                                  // o-quadrant per wave
  f4v acc[5][5];
#pragma unroll
  for (int mf = 0; mf < 5; ++mf) {
    float bv[4];
#pragma unroll
    for (int rr = 0; rr < 4; ++rr) {
      int o = ob + mf * 16 + quad * 4 + rr;
      bv[rr] = (o < DDIM) ? bias[o] : 0.0f;
    }
#pragma unroll
    for (int nf = 0; nf < 5; ++nf) {
      acc[mf][nf][0] = bv[0]; acc[mf][nf][1] = bv[1];
      acc[mf][nf][2] = bv[2]; acc[mf][nf][3] = bv[3];
    }
  }
  // A-frag (kc,it,mf) at wl[kc*DPAD*DPAD + mf*16*DPAD + it*32]
  const unsigned short* wl = wT + (size_t)(ob + l15) * DPAD + quad * 8;
  s8v Aping[5], Apong[5];
#pragma unroll
  for (int mf = 0; mf < 5; ++mf) Aping[mf] = *(const s8v*)&wl[mf * 16 * DPAD];        // (0,0)
#pragma unroll
  for (int mf = 0; mf < 5; ++mf) Apong[mf] = *(const s8v*)&wl[mf * 16 * DPAD + 32];   // (0,1)
  for (int ii = 0; ii < 100; ii += 2) {
    // ---- even sub-iter: frags (ii) in Aping
    {
      int kc = ii / 10, it = ii % 10;
      s8v Bv[5];
#pragma unroll
      for (int nf = 0; nf < 5; ++nf)
        Bv[nf] = *(const s8v*)&xls[(nf * 16 + l15 + kc) * CSTRIDE + it * 32 + quad * 8];
#pragma unroll
      for (int mf = 0; mf < 5; ++mf)
#pragma unroll
        for (int nf = 0; nf < 5; ++nf)
          acc[mf][nf] = __builtin_amdgcn_mfma_f32_16x16x32_bf16(Aping[mf], Bv[nf], acc[mf][nf], 0, 0, 0);
      int p = ii + 2;
      if (p < 100) {
        int kp = p / 10, itp = p % 10;
        const unsigned short* wp = wl + (size_t)kp * (DPAD * DPAD) + itp * 32;
#pragma unroll
        for (int mf = 0; mf < 5; ++mf) Aping[mf] = *(const s8v*)&wp[mf * 16 * DPAD];
      }
    }
    // ---- odd sub-iter: frags (ii+1) in Apong
    {
      int kc = (ii + 1) / 10, it = (ii + 1) % 10;
      s8v Bv[5];
#pragma unroll
      for (int nf = 0; nf < 5; ++nf)
        Bv[nf] = *(const s8v*)&xls[(nf * 16 + l15 + kc) * CSTRIDE + it * 32 + quad * 8];
#pragma unroll
      for (int mf = 0; mf < 5; ++mf)
#pragma unroll
        for (int nf = 0; nf < 5; ++nf)
          acc[mf][nf] = __builtin_amdgcn_mfma_f32_16x16x32_bf16(Apong[mf], Bv[nf], acc[mf][nf], 0, 0, 0);
      int p = ii + 3;
      if (p < 100) {
        int kp = p / 10, itp = p % 10;
        const unsigned short* wp = wl + (size_t)kp * (DPAD * DPAD) + itp * 32;
#pragma unroll
        for (int mf = 0; mf < 5; ++mf) Apong[mf] = *(const s8v*)&wp[mf * 16 * DPAD];
      }
    }
  }
#pragma unroll
  for (int mf = 0; mf < 5; ++mf) {
    int obase = ob + mf * 16 + quad * 4;
#pragma unroll
    for (int nf = 0; nf < 5; ++nf) {
      int t = t0 + nf * 16 + l15;            // always < TALLOC (26x80 = 2080 exact)
      bool live = t < TPRIME;
      unsigned short pk[4];
#pragma unroll
      for (int rr = 0; rr < 4; ++rr)
        pk[rr] = live ? f2bf(fmaxf(acc[mf][nf][rr], 0.0f)) : (unsigned short)0;
      *(uint2*)&h[((size_t)b * TALLOC + t) * DPAD + obase] = *(uint2*)pk;
    }
  }
}

// ---- K3: scores (U . h) via MFMA + fused softmax-weighted mean.
// r11: REVERT to the r5/r6 local optimum (119-121us, the best of 6 structural
// attempts: r6 tweaks null, r7 T15 spilled, r8 8-wave +13, r9 no-LDS +330,
// r10 dist-2+stagger +32). Structure: 4 waves, depth-1 DMA double-buffer
// (2 x 20480B), vmcnt(0)+barrier per tile, all 560 blocks co-resident at
// (256,3). A[2][10] in AGPRs (r6 finding). Unmasked softmax (tail h rows are
// exact zeros -> e=1) + (-23) phantom-column correction; setprio on MFMA.
__global__ __launch_bounds__(256, 3) void attn_mfma_kernel(
    const unsigned short* __restrict__ h, const unsigned short* __restrict__ Ub,
    const float* __restrict__ fcb, float* __restrict__ out) {
  __shared__ unsigned short hls[2 * TSTG * DPAD];   // 2 x 10240 elems = 40960B
  int b = blockIdx.x & 7, lb = blockIdx.x >> 3;
  int tid = threadIdx.x;
  int w = tid >> 6, lane = tid & 63;
  int l15 = lane & 15, quad = lane >> 4;
  const unsigned short* hb = h + (size_t)b * TALLOC * DPAD;

  // A fragments (U): wave covers 32 l-rows
  s8v A[2][10];
  {
    int lr0 = lb * 128 + w * 32 + l15;
#pragma unroll
    for (int mf = 0; mf < 2; ++mf) {
      int lr = lr0 + mf * 16;
      if (lr >= LPAD) lr = LPAD - 1;          // clamped rows masked at store
      const unsigned short* up = Ub + (size_t)lr * DPAD + quad * 8;
#pragma unroll
      for (int kc = 0; kc < 10; ++kc)
        A[mf][kc] = *(const s8v*)&up[kc * 32];
    }
  }

  // DMA staging map: wave w fills LDS elems [w*2560, w*2560+2560) in 5 x 1KB.
  // lane's LDS chunk g = w*320 + j*64 + lane -> row r = g/40, chunk c = g%40;
  // global source chunk = c ^ (r&7)  (involution, same XOR on read side)
  int srcoff[5];
#pragma unroll
  for (int j = 0; j < 5; ++j) {
    int g = w * 320 + j * 64 + lane;
    int r = g / 40, c = g % 40;
    srcoff[j] = r * DPAD + ((c ^ (r & 7)) * 8);
  }

  // prologue: DMA tile 0 -> buf0
#pragma unroll
  for (int j = 0; j < 5; ++j)
    __builtin_amdgcn_global_load_lds((gas_ptr)(const void*)(hb + srcoff[j]),
                                     (las_ptr)(void*)&hls[w * 2560 + j * 512],
                                     16, 0, 0);
  asm volatile("s_waitcnt vmcnt(0)" ::: "memory");
  __builtin_amdgcn_s_barrier();

  float se[2][4], sw[2][4];
#pragma unroll
  for (int mf = 0; mf < 2; ++mf)
#pragma unroll
    for (int r = 0; r < 4; ++r) { se[mf][r] = 0.0f; sw[mf][r] = 0.0f; }

  int xr8 = (l15 & 7) * 8;            // read-side XOR (elem units)
  int rowb0 = l15 * DPAD;             // nf=0 row base
  int rowb1 = (16 + l15) * DPAD;      // nf=1 row base
  int bufsel = 0;
  const f4v vzero = {0.0f, 0.0f, 0.0f, 0.0f};
  for (int t = 0; t < NTT; ++t) {
    // issue DMA for tile t+1 into the other buffer (latency hidden by compute)
    if (t + 1 < NTT) {
      const unsigned short* src = hb + (size_t)(t + 1) * TSTG * DPAD;
      int dstb = (bufsel ^ 1) * 10240 + w * 2560;
#pragma unroll
      for (int j = 0; j < 5; ++j)
        __builtin_amdgcn_global_load_lds((gas_ptr)(const void*)(src + srcoff[j]),
                                         (las_ptr)(void*)&hls[dstb + j * 512],
                                         16, 0, 0);
    }
    const unsigned short* bufc = &hls[bufsel * 10240];
    f4v a00, a01, a10, a11;
    __builtin_amdgcn_s_setprio(1);
    {
      int ko = (quad * 8) ^ xr8;
      s8v Bv0 = *(const s8v*)&bufc[rowb0 + ko];
      s8v Bv1 = *(const s8v*)&bufc[rowb1 + ko];
      a00 = __builtin_amdgcn_mfma_f32_16x16x32_bf16(A[0][0], Bv0, vzero, 0, 0, 0);
      a01 = __builtin_amdgcn_mfma_f32_16x16x32_bf16(A[0][0], Bv1, vzero, 0, 0, 0);
      a10 = __builtin_amdgcn_mfma_f32_16x16x32_bf16(A[1][0], Bv0, vzero, 0, 0, 0);
      a11 = __builtin_amdgcn_mfma_f32_16x16x32_bf16(A[1][0], Bv1, vzero, 0, 0, 0);
    }
#pragma unroll
    for (int kc = 1; kc < 10; ++kc) {
      int ko = (kc * 32 + quad * 8) ^ xr8;
      s8v Bv0 = *(const s8v*)&bufc[rowb0 + ko];
      s8v Bv1 = *(const s8v*)&bufc[rowb1 + ko];
      a00 = __builtin_amdgcn_mfma_f32_16x16x32_bf16(A[0][kc], Bv0, a00, 0, 0, 0);
      a01 = __builtin_amdgcn_mfma_f32_16x16x32_bf16(A[0][kc], Bv1, a01, 0, 0, 0);
      a10 = __builtin_amdgcn_mfma_f32_16x16x32_bf16(A[1][kc], Bv0, a10, 0, 0, 0);
      a11 = __builtin_amdgcn_mfma_f32_16x16x32_bf16(A[1][kc], Bv1, a11, 0, 0, 0);
    }
    __builtin_amdgcn_s_setprio(0);
    // unmasked fused softmax accumulation (tail h rows are exact zeros ->
    // s=0 -> e=1; corrected after the reduction)
#pragma unroll
    for (int r = 0; r < 4; ++r) {
      float s0 = a00[r], s1 = a01[r];
      float e0 = __expf(s0), e1 = __expf(s1);
      se[0][r] += e0 + e1;
      sw[0][r] = fmaf(e0, s0, sw[0][r]);
      sw[0][r] = fmaf(e1, s1, sw[0][r]);
      float s2 = a10[r], s3 = a11[r];
      float e2 = __expf(s2), e3 = __expf(s3);
      se[1][r] += e2 + e3;
      sw[1][r] = fmaf(e2, s2, sw[1][r]);
      sw[1][r] = fmaf(e3, s3, sw[1][r]);
    }
    // drain this iter's DMA (issued a full tile of compute ago), sync, swap
    asm volatile("s_waitcnt vmcnt(0)" ::: "memory");
    __builtin_amdgcn_s_barrier();
    bufsel ^= 1;
  }

  // reduce over the 16 t-columns (l15 lanes); subtract the 23 phantom columns
  // (TALLOC - TPRIME, each contributing exactly exp(0)=1) from the denominator.
#pragma unroll
  for (int mf = 0; mf < 2; ++mf)
#pragma unroll
    for (int r = 0; r < 4; ++r) {
      float a = se[mf][r], c = sw[mf][r];
#pragma unroll
      for (int off = 1; off < 16; off <<= 1) {
        a += __shfl_xor(a, off, 64);
        c += __shfl_xor(c, off, 64);
      }
      if (l15 == 0) {
        int l = lb * 128 + w * 32 + mf * 16 + quad * 4 + r;
        if (l < LDIM) out[(size_t)b * LDIM + l] = c / (a - 23.0f) + fcb[l];
      }
    }
}

extern "C" void kernel_launch(void* const* d_in, const int* in_sizes, int n_in,
                              void* d_out, int out_size, void* d_ws, size_t ws_size,
                              hipStream_t stream) {
  const int*   ids     = (const int*)d_in[0];
  const float* embed_w = (const float*)d_in[1];
  const float* conv_w  = (const float*)d_in[2];
  const float* conv_b  = (const float*)d_in[3];
  const float* U       = (const float*)d_in[4];
  const float* fc_bias = (const float*)d_in[5];
  float* out = (float*)d_out;

  unsigned char* p = (unsigned char*)d_ws;
  unsigned short* hb = (unsigned short*)p;                 p += (size_t)BATCH * TALLOC * DPAD * 2;
  unsigned short* wT = (unsigned short*)p;                 p += (size_t)KSZ * DPAD * DPAD * 2;
  unsigned short* Ub = (unsigned short*)p;

  hipLaunchKernelGGL(prep_kernel, dim3(KSZ * DPAD + LPAD), dim3(256), 0, stream,
                     conv_w, U, wT, Ub);
  hipLaunchKernelGGL(conv_mfma_kernel, dim3(BATCH * 26), dim3(256), 0, stream,
                     ids, embed_w, wT, conv_b, hb);
  hipLaunchKernelGGL(attn_mfma_kernel, dim3(BATCH * LBLK), dim3(256), 0, stream,
                     hb, Ub, fc_bias, out);
}